// Round 7
// baseline (296.285 us; speedup 1.0000x reference)
//
#include <hip/hip_runtime.h>

#define N_NODES 100000
#define N_EDGES 1600000
#define D 64
#define NB 128               // edge-chunk blocks for count/scatter
#define EPB (N_EDGES / NB)   // 12500 edges per block
#define NBUCK 3125           // 100000 >> 5 buckets of 32 nodes
#define NBUCK_PAD 3136       // 32-multiple padding (98 groups of 32)
#define NGRP 98              // NBUCK_PAD / 32
#define CAP 1024             // records per in-LDS sort chunk (buckets avg ~512)
#define AST 68               // padded LDS row stride (bank-conflict-free)

// -------- K1: per-block coarse counts (col-buckets and row-buckets) --------
__global__ __launch_bounds__(512) void count_kernel(const int* __restrict__ row,
                                                    const int* __restrict__ col,
                                                    int* __restrict__ matC,
                                                    int* __restrict__ matR) {
    __shared__ int cC[NBUCK_PAD];
    __shared__ int cR[NBUCK_PAD];
    int t = threadIdx.x;
    for (int j = t; j < NBUCK_PAD; j += 512) { cC[j] = 0; cR[j] = 0; }
    __syncthreads();
    int base = blockIdx.x * EPB;
    for (int i = t; i < EPB; i += 512) {
        int e = base + i;
        atomicAdd(&cC[col[e] >> 5], 1);
        atomicAdd(&cR[row[e] >> 5], 1);
    }
    __syncthreads();
    int* mc = matC + (size_t)blockIdx.x * NBUCK_PAD;
    int* mr = matR + (size_t)blockIdx.x * NBUCK_PAD;
    for (int j = t; j < NBUCK_PAD; j += 512) { mc[j] = cC[j]; mr[j] = cR[j]; }
}

// -------- K2a: tiled per-bucket exclusive scan over NB blocks (in place) ---
__global__ __launch_bounds__(256) void blockscan_kernel(int* __restrict__ matC,
                                                        int* __restrict__ matR,
                                                        int* __restrict__ totalsC,
                                                        int* __restrict__ totalsR) {
    int which = blockIdx.x / NGRP;
    int grp   = blockIdx.x % NGRP;
    int* mat    = which ? matR : matC;
    int* totals = which ? totalsR : totalsC;
    int j0 = grp * 32;
    __shared__ int tile[NB][33];
    int t = threadIdx.x;
    int r = t >> 1;          // 0..127
    int h = t & 1;           // 0..1
    {
        const int* src = mat + (size_t)r * NBUCK_PAD + j0 + h * 16;
        int4 v0 = *(const int4*)(src + 0);
        int4 v1 = *(const int4*)(src + 4);
        int4 v2 = *(const int4*)(src + 8);
        int4 v3 = *(const int4*)(src + 12);
        int cb = h * 16;
        tile[r][cb+0]=v0.x;  tile[r][cb+1]=v0.y;  tile[r][cb+2]=v0.z;  tile[r][cb+3]=v0.w;
        tile[r][cb+4]=v1.x;  tile[r][cb+5]=v1.y;  tile[r][cb+6]=v1.z;  tile[r][cb+7]=v1.w;
        tile[r][cb+8]=v2.x;  tile[r][cb+9]=v2.y;  tile[r][cb+10]=v2.z; tile[r][cb+11]=v2.w;
        tile[r][cb+12]=v3.x; tile[r][cb+13]=v3.y; tile[r][cb+14]=v3.z; tile[r][cb+15]=v3.w;
    }
    __syncthreads();
    int g = t >> 3;          // bucket within tile, 0..31
    int l = t & 7;           // lane in 8-wide scan group
    int rows0 = l * 16;
    int vals[16];
    int s = 0;
    #pragma unroll
    for (int i = 0; i < 16; ++i) { vals[i] = tile[rows0 + i][g]; s += vals[i]; }
    int inc = s;
    #pragma unroll
    for (int d = 1; d < 8; d <<= 1) {
        int u = __shfl_up(inc, d, 8);
        if (l >= d) inc += u;
    }
    int excl = inc - s;
    #pragma unroll
    for (int i = 0; i < 16; ++i) { int e2 = excl; excl += vals[i]; tile[rows0 + i][g] = e2; }
    if (l == 7) totals[j0 + g] = inc;
    __syncthreads();
    {
        int* dst = mat + (size_t)r * NBUCK_PAD + j0 + h * 16;
        int cb = h * 16;
        int4 v0 = make_int4(tile[r][cb+0],  tile[r][cb+1],  tile[r][cb+2],  tile[r][cb+3]);
        int4 v1 = make_int4(tile[r][cb+4],  tile[r][cb+5],  tile[r][cb+6],  tile[r][cb+7]);
        int4 v2 = make_int4(tile[r][cb+8],  tile[r][cb+9],  tile[r][cb+10], tile[r][cb+11]);
        int4 v3 = make_int4(tile[r][cb+12], tile[r][cb+13], tile[r][cb+14], tile[r][cb+15]);
        *(int4*)(dst + 0)  = v0;
        *(int4*)(dst + 4)  = v1;
        *(int4*)(dst + 8)  = v2;
        *(int4*)(dst + 12) = v3;
    }
}

// -------- K2b: exclusive scan of bucket totals (one block per array) -------
__global__ __launch_bounds__(256) void totscan_kernel(const int* __restrict__ totalsC,
                                                      int* __restrict__ bstartC,
                                                      const int* __restrict__ totalsR,
                                                      int* __restrict__ bstartR) {
    const int* tot = blockIdx.x ? totalsR : totalsC;
    int* bst       = blockIdx.x ? bstartR : bstartC;
    const int CH = (NBUCK_PAD + 255) / 256;  // 13
    __shared__ int lds[256];
    int t = threadIdx.x;
    int local[CH];
    int s = 0;
    for (int i = 0; i < CH; ++i) {
        int idx = t * CH + i;
        local[i] = (idx < NBUCK_PAD) ? tot[idx] : 0;
        s += local[i];
    }
    lds[t] = s;
    __syncthreads();
    for (int off = 1; off < 256; off <<= 1) {
        int u = (t >= off) ? lds[t - off] : 0;
        __syncthreads();
        lds[t] += u;
        __syncthreads();
    }
    int excl = (t > 0) ? lds[t - 1] : 0;
    for (int i = 0; i < CH; ++i) {
        int idx = t * CH + i;
        if (idx < NBUCK_PAD) bst[idx] = excl;
        excl += local[i];
    }
}

// -------- K3: scatter edges into bucket order, LDS cursors, NO globals -----
__global__ __launch_bounds__(512) void scatter_kernel(const int* __restrict__ row,
                                                      const int* __restrict__ col,
                                                      const float* __restrict__ w,
                                                      const int* __restrict__ matC,
                                                      const int* __restrict__ matR,
                                                      const int* __restrict__ bstartC,
                                                      const int* __restrict__ bstartR,
                                                      int2* __restrict__ crecs,
                                                      unsigned* __restrict__ rrecs) {
    __shared__ int cursC[NBUCK];
    __shared__ int cursR[NBUCK];
    int t = threadIdx.x;
    const int* offC = matC + (size_t)blockIdx.x * NBUCK_PAD;
    const int* offR = matR + (size_t)blockIdx.x * NBUCK_PAD;
    for (int j = t; j < NBUCK; j += 512) {
        cursC[j] = bstartC[j] + offC[j];
        cursR[j] = bstartR[j] + offR[j];
    }
    __syncthreads();
    int base = blockIdx.x * EPB;
    for (int i = t; i < EPB; i += 512) {
        int e = base + i;
        int r = row[e];
        int c = col[e];
        float we = w[e];
        int pC = atomicAdd(&cursC[c >> 5], 1);
        crecs[pC] = make_int2(r | ((c & 31) << 17), __float_as_int(we));
        int pR = atomicAdd(&cursR[r >> 5], 1);
        rrecs[pR] = (__float_as_uint(we) & ~31u) | (unsigned)(r & 31);
    }
}

// -------- K4: per row-bucket degree reduction -> dinv --------
__global__ __launch_bounds__(256) void deg_kernel(const unsigned* __restrict__ rrecs,
                                                  const int* __restrict__ bstartR,
                                                  const int* __restrict__ totalsR,
                                                  float* __restrict__ dinv) {
    __shared__ float acc[32];
    int t = threadIdx.x;
    int b = blockIdx.x;
    if (t < 32) acc[t] = 0.f;
    __syncthreads();
    int base = bstartR[b];
    int cnt  = totalsR[b];
    for (int i = t; i < cnt; i += 256) {
        unsigned v = rrecs[base + i];
        atomicAdd(&acc[v & 31u], __uint_as_float(v & ~31u));
    }
    __syncthreads();
    if (t < 32) {
        float d = acc[t];
        dinv[b * 32 + t] = d > 0.f ? rsqrtf(d) : 0.f;
    }
}

#define FLUSH()                                                                \
    do { if (cur >= 0) {                                                       \
        float* ap = accL + cur * AST + (j << 3);                               \
        atomicAdd(ap + 0, a0.x); atomicAdd(ap + 1, a0.y);                      \
        atomicAdd(ap + 2, a0.z); atomicAdd(ap + 3, a0.w);                      \
        atomicAdd(ap + 4, a1.x); atomicAdd(ap + 5, a1.y);                      \
        atomicAdd(ap + 6, a1.z); atomicAdd(ap + 7, a1.w);                      \
    }                                                                          \
    a0 = make_float4(0.f,0.f,0.f,0.f); a1 = make_float4(0.f,0.f,0.f,0.f);      \
    } while (0)

#define PROC(e, v0, v1)                                                        \
    do { int nd = ((unsigned)(e).x) >> 17;                                     \
        if (nd != cur) { FLUSH(); cur = nd; }                                  \
        float cc = __int_as_float((e).y);                                      \
        a0.x += cc * (v0).x; a0.y += cc * (v0).y;                              \
        a0.z += cc * (v0).z; a0.w += cc * (v0).w;                              \
        a1.x += cc * (v1).x; a1.y += cc * (v1).y;                              \
        a1.z += cc * (v1).z; a1.w += cc * (v1).w;                              \
    } while (0)

// -------- K5: fused sort + BALANCED register gather + matmul --------
// Block = one bucket of 32 nodes; 256 threads = 32 groups x 8 lanes.
// Each group processes an EQUAL slice of the node-sorted record list,
// register-accumulating and flushing to the LDS row only on node change.
__global__ __launch_bounds__(256) void gather_out_kernel(
        const int2* __restrict__ crecs, const int* __restrict__ bstartC,
        const int* __restrict__ totalsC, const float* __restrict__ dinv,
        const float* __restrict__ x,
        const float* __restrict__ W0, const float* __restrict__ W1,
        const float* __restrict__ bias, float* __restrict__ out) {
    __shared__ __align__(16) char smemA[32 * AST * 4];  // srt (8192) | xs
    __shared__ __align__(16) char smemB[32 * AST * 4];  // accL / ts
    __shared__ int cnt32[32];
    __shared__ int cur32[32];
    int2*  srt  = (int2*)smemA;
    float* xs   = (float*)smemA;
    float* accL = (float*)smemB;
    float* ts   = accL;

    int tid = threadIdx.x;
    int b   = blockIdx.x;
    int n0  = b * 32;
    int g   = tid >> 3;      // group 0..31 (also node-slot in matmul phase)
    int j   = tid & 7;       // lane owns features 8j..8j+7

    for (int i = tid; i < 32 * AST; i += 256) accL[i] = 0.f;

    int base = bstartC[b];
    int cnt  = totalsC[b];
    const float* xj = x + (size_t)(j << 3);

    for (int cb = 0; cb < cnt; cb += CAP) {
        int m = min(CAP, cnt - cb);
        if (tid < 32) cnt32[tid] = 0;
        __syncthreads();
        // pass 1: count nodes (read key dword from global; L2-hot for pass 2)
        for (int i = tid; i < m; i += 256)
            atomicAdd(&cnt32[((unsigned)crecs[base + cb + i].x) >> 17], 1);
        __syncthreads();
        if (tid < 32) {               // exclusive scan via shfl (wave 0)
            int v = cnt32[tid];
            int inc = v;
            #pragma unroll
            for (int d = 1; d < 32; d <<= 1) {
                int u = __shfl_up(inc, d, 32);
                if (tid >= d) inc += u;
            }
            cur32[tid] = inc - v;
        }
        __syncthreads();
        // pass 2: place into srt (node-sorted), dinv[r] folded into weight
        for (int i = tid; i < m; i += 256) {
            int2 rec = crecs[base + cb + i];
            int r = rec.x & 0x1FFFF;
            rec.y = __float_as_int(__int_as_float(rec.y) * dinv[r]);
            int p = atomicAdd(&cur32[((unsigned)rec.x) >> 17], 1);
            srt[p] = rec;
        }
        __syncthreads();
        // balanced accumulation: group g takes records [lo, hi)
        int q   = m >> 5;
        int rem = m & 31;
        int lo  = g * q + (g < rem ? g : rem);
        int hi  = lo + q + (g < rem ? 1 : 0);
        float4 a0 = make_float4(0.f,0.f,0.f,0.f);
        float4 a1 = make_float4(0.f,0.f,0.f,0.f);
        int cur = -1;
        int k = lo;
        for (; k + 3 < hi; k += 4) {
            int2 e0 = srt[k + 0];
            int2 e1 = srt[k + 1];
            int2 e2 = srt[k + 2];
            int2 e3 = srt[k + 3];
            const float* p0 = xj + (size_t)(e0.x & 0x1FFFF) * D;
            const float* p1 = xj + (size_t)(e1.x & 0x1FFFF) * D;
            const float* p2 = xj + (size_t)(e2.x & 0x1FFFF) * D;
            const float* p3 = xj + (size_t)(e3.x & 0x1FFFF) * D;
            float4 v00 = *(const float4*)p0, v01 = *(const float4*)(p0 + 4);
            float4 v10 = *(const float4*)p1, v11 = *(const float4*)(p1 + 4);
            float4 v20 = *(const float4*)p2, v21 = *(const float4*)(p2 + 4);
            float4 v30 = *(const float4*)p3, v31 = *(const float4*)(p3 + 4);
            PROC(e0, v00, v01);
            PROC(e1, v10, v11);
            PROC(e2, v20, v21);
            PROC(e3, v30, v31);
        }
        for (; k < hi; ++k) {
            int2 e0 = srt[k];
            const float* p0 = xj + (size_t)(e0.x & 0x1FFFF) * D;
            float4 v00 = *(const float4*)p0, v01 = *(const float4*)(p0 + 4);
            PROC(e0, v00, v01);
        }
        FLUSH();
        __syncthreads();   // flushes + srt reads done before next chunk
    }

    // scale ts = -dinv[n] * accL in place (thread owns its (g,j) slice)
    {
        float dn = -dinv[n0 + g];
        float* tp = ts + g * AST + (j << 3);
        float4 t0 = *(float4*)tp;
        float4 t1 = *(float4*)(tp + 4);
        t0.x *= dn; t0.y *= dn; t0.z *= dn; t0.w *= dn;
        t1.x *= dn; t1.y *= dn; t1.z *= dn; t1.w *= dn;
        *(float4*)tp       = t0;
        *(float4*)(tp + 4) = t1;
    }
    // stage xs (overwrites srt region — dead after last chunk barrier)
    for (int i = tid; i < 512; i += 256) {          // 512 float4 = 32x64 floats
        int nn = i >> 4;
        int kk = (i & 15) << 2;
        *(float4*)&xs[nn * AST + kk] = *(const float4*)(x + (size_t)n0 * D + i * 4);
    }
    __syncthreads();

    int jl = j << 3;
    float4 o0 = *(const float4*)(bias + jl);
    float4 o1 = *(const float4*)(bias + jl + 4);
    for (int k = 0; k < D; k += 4) {
        float4 av = *(const float4*)&xs[g * AST + k];
        float4 tv = *(const float4*)&ts[g * AST + k];
        #pragma unroll
        for (int u = 0; u < 4; ++u) {
            float a = (u == 0) ? av.x : (u == 1) ? av.y : (u == 2) ? av.z : av.w;
            float t = (u == 0) ? tv.x : (u == 1) ? tv.y : (u == 2) ? tv.z : tv.w;
            const float4 w00 = *(const float4*)(W0 + (size_t)(k + u) * D + jl);
            const float4 w01 = *(const float4*)(W0 + (size_t)(k + u) * D + jl + 4);
            const float4 w10 = *(const float4*)(W1 + (size_t)(k + u) * D + jl);
            const float4 w11 = *(const float4*)(W1 + (size_t)(k + u) * D + jl + 4);
            o0.x += a * w00.x + t * w10.x;
            o0.y += a * w00.y + t * w10.y;
            o0.z += a * w00.z + t * w10.z;
            o0.w += a * w00.w + t * w10.w;
            o1.x += a * w01.x + t * w11.x;
            o1.y += a * w01.y + t * w11.y;
            o1.z += a * w01.z + t * w11.z;
            o1.w += a * w01.w + t * w11.w;
        }
    }
    float* op = out + (size_t)(n0 + g) * D + jl;
    *(float4*)op       = o0;
    *(float4*)(op + 4) = o1;
}

extern "C" void kernel_launch(void* const* d_in, const int* in_sizes, int n_in,
                              void* d_out, int out_size, void* d_ws, size_t ws_size,
                              hipStream_t stream) {
    const float* x    = (const float*)d_in[0];
    const int*   eidx = (const int*)d_in[1];   // [2, E]: row then col
    const float* ew   = (const float*)d_in[2];
    const float* W0   = (const float*)d_in[3];
    const float* W1   = (const float*)d_in[4];
    const float* b    = (const float*)d_in[5];
    float* out = (float*)d_out;

    const int* row = eidx;
    const int* col = eidx + N_EDGES;

    // Workspace layout (4B words), fully overwritten each call, no memset.
    int2*     crecs   = (int2*)d_ws;                                   // E int2
    unsigned* rrecs   = (unsigned*)((int*)d_ws + 2 * (size_t)N_EDGES); // E
    int*      matC    = (int*)rrecs + N_EDGES;                         // NB*NBUCK_PAD
    int*      matR    = matC + (size_t)NB * NBUCK_PAD;                 // NB*NBUCK_PAD
    int*      totalsC = matR + (size_t)NB * NBUCK_PAD;                 // NBUCK_PAD
    int*      bstartC = totalsC + NBUCK_PAD;                           // NBUCK_PAD
    int*      totalsR = bstartC + NBUCK_PAD;                           // NBUCK_PAD
    int*      bstartR = totalsR + NBUCK_PAD;                           // NBUCK_PAD
    float*    dinv    = (float*)(bstartR + NBUCK_PAD);                 // N

    count_kernel     <<<NB, 512, 0, stream>>>(row, col, matC, matR);
    blockscan_kernel <<<2 * NGRP, 256, 0, stream>>>(matC, matR, totalsC, totalsR);
    totscan_kernel   <<<2, 256, 0, stream>>>(totalsC, bstartC, totalsR, bstartR);
    scatter_kernel   <<<NB, 512, 0, stream>>>(row, col, ew, matC, matR,
                                              bstartC, bstartR, crecs, rrecs);
    deg_kernel       <<<NBUCK, 256, 0, stream>>>(rrecs, bstartR, totalsR, dinv);
    gather_out_kernel<<<NBUCK, 256, 0, stream>>>(crecs, bstartC, totalsC, dinv,
                                                 x, W0, W1, b, out);
}

// Round 8
// 288.849 us; speedup vs baseline: 1.0257x; 1.0257x over previous
//
#include <hip/hip_runtime.h>

#define N_NODES 100000
#define N_EDGES 1600000
#define D 64
#define NB 128               // edge-chunk blocks for count/scatter
#define EPB (N_EDGES / NB)   // 12500 edges per block
#define NBUCK 3125           // 100000 >> 5 buckets of 32 nodes
#define NBUCK_PAD 3136       // 32-multiple padding (98 groups of 32)
#define NGRP 98              // NBUCK_PAD / 32
#define CAP 1024             // records per in-LDS sort chunk (buckets avg ~512)
#define AST 68               // padded LDS row stride (bank-conflict-free)

// -------- K0: x (fp32) -> xh (bf16, RNE) --------
__device__ __forceinline__ unsigned bf16rne(float f) {
    unsigned u = __float_as_uint(f);
    return (u + 0x7FFFu + ((u >> 16) & 1u)) >> 16;
}
__global__ __launch_bounds__(256) void tobf16_kernel(const float* __restrict__ x,
                                                     ushort* __restrict__ xh) {
    int i = (blockIdx.x * 256 + threadIdx.x) * 8;   // 6.4M elems / 8 = 800k threads
    float4 a = *(const float4*)(x + i);
    float4 b = *(const float4*)(x + i + 4);
    uint4 o;
    o.x = bf16rne(a.x) | (bf16rne(a.y) << 16);
    o.y = bf16rne(a.z) | (bf16rne(a.w) << 16);
    o.z = bf16rne(b.x) | (bf16rne(b.y) << 16);
    o.w = bf16rne(b.z) | (bf16rne(b.w) << 16);
    *(uint4*)(xh + i) = o;
}

// -------- K1: per-block coarse counts (col-buckets and row-buckets) --------
__global__ __launch_bounds__(512) void count_kernel(const int* __restrict__ row,
                                                    const int* __restrict__ col,
                                                    int* __restrict__ matC,
                                                    int* __restrict__ matR) {
    __shared__ int cC[NBUCK_PAD];
    __shared__ int cR[NBUCK_PAD];
    int t = threadIdx.x;
    for (int j = t; j < NBUCK_PAD; j += 512) { cC[j] = 0; cR[j] = 0; }
    __syncthreads();
    int base = blockIdx.x * EPB;
    for (int i = t; i < EPB; i += 512) {
        int e = base + i;
        atomicAdd(&cC[col[e] >> 5], 1);
        atomicAdd(&cR[row[e] >> 5], 1);
    }
    __syncthreads();
    int* mc = matC + (size_t)blockIdx.x * NBUCK_PAD;
    int* mr = matR + (size_t)blockIdx.x * NBUCK_PAD;
    for (int j = t; j < NBUCK_PAD; j += 512) { mc[j] = cC[j]; mr[j] = cR[j]; }
}

// -------- K2a: tiled per-bucket exclusive scan over NB blocks (in place) ---
__global__ __launch_bounds__(256) void blockscan_kernel(int* __restrict__ matC,
                                                        int* __restrict__ matR,
                                                        int* __restrict__ totalsC,
                                                        int* __restrict__ totalsR) {
    int which = blockIdx.x / NGRP;
    int grp   = blockIdx.x % NGRP;
    int* mat    = which ? matR : matC;
    int* totals = which ? totalsR : totalsC;
    int j0 = grp * 32;
    __shared__ int tile[NB][33];
    int t = threadIdx.x;
    int r = t >> 1;          // 0..127
    int h = t & 1;           // 0..1
    {
        const int* src = mat + (size_t)r * NBUCK_PAD + j0 + h * 16;
        int4 v0 = *(const int4*)(src + 0);
        int4 v1 = *(const int4*)(src + 4);
        int4 v2 = *(const int4*)(src + 8);
        int4 v3 = *(const int4*)(src + 12);
        int cb = h * 16;
        tile[r][cb+0]=v0.x;  tile[r][cb+1]=v0.y;  tile[r][cb+2]=v0.z;  tile[r][cb+3]=v0.w;
        tile[r][cb+4]=v1.x;  tile[r][cb+5]=v1.y;  tile[r][cb+6]=v1.z;  tile[r][cb+7]=v1.w;
        tile[r][cb+8]=v2.x;  tile[r][cb+9]=v2.y;  tile[r][cb+10]=v2.z; tile[r][cb+11]=v2.w;
        tile[r][cb+12]=v3.x; tile[r][cb+13]=v3.y; tile[r][cb+14]=v3.z; tile[r][cb+15]=v3.w;
    }
    __syncthreads();
    int g = t >> 3;          // bucket within tile, 0..31
    int l = t & 7;           // lane in 8-wide scan group
    int rows0 = l * 16;
    int vals[16];
    int s = 0;
    #pragma unroll
    for (int i = 0; i < 16; ++i) { vals[i] = tile[rows0 + i][g]; s += vals[i]; }
    int inc = s;
    #pragma unroll
    for (int d = 1; d < 8; d <<= 1) {
        int u = __shfl_up(inc, d, 8);
        if (l >= d) inc += u;
    }
    int excl = inc - s;
    #pragma unroll
    for (int i = 0; i < 16; ++i) { int e2 = excl; excl += vals[i]; tile[rows0 + i][g] = e2; }
    if (l == 7) totals[j0 + g] = inc;
    __syncthreads();
    {
        int* dst = mat + (size_t)r * NBUCK_PAD + j0 + h * 16;
        int cb = h * 16;
        int4 v0 = make_int4(tile[r][cb+0],  tile[r][cb+1],  tile[r][cb+2],  tile[r][cb+3]);
        int4 v1 = make_int4(tile[r][cb+4],  tile[r][cb+5],  tile[r][cb+6],  tile[r][cb+7]);
        int4 v2 = make_int4(tile[r][cb+8],  tile[r][cb+9],  tile[r][cb+10], tile[r][cb+11]);
        int4 v3 = make_int4(tile[r][cb+12], tile[r][cb+13], tile[r][cb+14], tile[r][cb+15]);
        *(int4*)(dst + 0)  = v0;
        *(int4*)(dst + 4)  = v1;
        *(int4*)(dst + 8)  = v2;
        *(int4*)(dst + 12) = v3;
    }
}

// -------- K2b: exclusive scan of bucket totals (one block per array) -------
__global__ __launch_bounds__(256) void totscan_kernel(const int* __restrict__ totalsC,
                                                      int* __restrict__ bstartC,
                                                      const int* __restrict__ totalsR,
                                                      int* __restrict__ bstartR) {
    const int* tot = blockIdx.x ? totalsR : totalsC;
    int* bst       = blockIdx.x ? bstartR : bstartC;
    const int CH = (NBUCK_PAD + 255) / 256;  // 13
    __shared__ int lds[256];
    int t = threadIdx.x;
    int local[CH];
    int s = 0;
    for (int i = 0; i < CH; ++i) {
        int idx = t * CH + i;
        local[i] = (idx < NBUCK_PAD) ? tot[idx] : 0;
        s += local[i];
    }
    lds[t] = s;
    __syncthreads();
    for (int off = 1; off < 256; off <<= 1) {
        int u = (t >= off) ? lds[t - off] : 0;
        __syncthreads();
        lds[t] += u;
        __syncthreads();
    }
    int excl = (t > 0) ? lds[t - 1] : 0;
    for (int i = 0; i < CH; ++i) {
        int idx = t * CH + i;
        if (idx < NBUCK_PAD) bst[idx] = excl;
        excl += local[i];
    }
}

// -------- K3: scatter edges into bucket order, LDS cursors, NO globals -----
// crec = row<<15 | coloff<<10 | w_q10   (4B, col-bucket order)
// rrec = (bits(w) & ~31) | (row&31)     (4B, row-bucket order)
__global__ __launch_bounds__(512) void scatter_kernel(const int* __restrict__ row,
                                                      const int* __restrict__ col,
                                                      const float* __restrict__ w,
                                                      const int* __restrict__ matC,
                                                      const int* __restrict__ matR,
                                                      const int* __restrict__ bstartC,
                                                      const int* __restrict__ bstartR,
                                                      unsigned* __restrict__ crecs,
                                                      unsigned* __restrict__ rrecs) {
    __shared__ int cursC[NBUCK];
    __shared__ int cursR[NBUCK];
    int t = threadIdx.x;
    const int* offC = matC + (size_t)blockIdx.x * NBUCK_PAD;
    const int* offR = matR + (size_t)blockIdx.x * NBUCK_PAD;
    for (int j = t; j < NBUCK; j += 512) {
        cursC[j] = bstartC[j] + offC[j];
        cursR[j] = bstartR[j] + offR[j];
    }
    __syncthreads();
    int base = blockIdx.x * EPB;
    for (int i = t; i < EPB; i += 512) {
        int e = base + i;
        int r = row[e];
        int c = col[e];
        float we = w[e];
        unsigned wq = (unsigned)min(1023, (int)(we * 1024.f + 0.5f));
        int pC = atomicAdd(&cursC[c >> 5], 1);
        crecs[pC] = ((unsigned)r << 15) | ((unsigned)(c & 31) << 10) | wq;
        int pR = atomicAdd(&cursR[r >> 5], 1);
        rrecs[pR] = (__float_as_uint(we) & ~31u) | (unsigned)(r & 31);
    }
}

// -------- K4: per row-bucket degree reduction -> dinv --------
__global__ __launch_bounds__(256) void deg_kernel(const unsigned* __restrict__ rrecs,
                                                  const int* __restrict__ bstartR,
                                                  const int* __restrict__ totalsR,
                                                  float* __restrict__ dinv) {
    __shared__ float acc[32];
    int t = threadIdx.x;
    int b = blockIdx.x;
    if (t < 32) acc[t] = 0.f;
    __syncthreads();
    int base = bstartR[b];
    int cnt  = totalsR[b];
    for (int i = t; i < cnt; i += 256) {
        unsigned v = rrecs[base + i];
        atomicAdd(&acc[v & 31u], __uint_as_float(v & ~31u));
    }
    __syncthreads();
    if (t < 32) {
        float d = acc[t];
        dinv[b * 32 + t] = d > 0.f ? rsqrtf(d) : 0.f;
    }
}

#define FMA_BF16(e, u)                                                         \
    do { float cc = __int_as_float((e).y);                                     \
        acc0.x += cc * __uint_as_float((u).x << 16);                           \
        acc0.y += cc * __uint_as_float((u).x & 0xFFFF0000u);                   \
        acc0.z += cc * __uint_as_float((u).y << 16);                           \
        acc0.w += cc * __uint_as_float((u).y & 0xFFFF0000u);                   \
        acc1.x += cc * __uint_as_float((u).z << 16);                           \
        acc1.y += cc * __uint_as_float((u).z & 0xFFFF0000u);                   \
        acc1.z += cc * __uint_as_float((u).w << 16);                           \
        acc1.w += cc * __uint_as_float((u).w & 0xFFFF0000u);                   \
    } while (0)

// -------- K5: fused sort + per-node register gather (bf16 x) + matmul ------
// Block = one bucket of 32 nodes; 256 threads = 32 node-groups x 8 lanes.
__global__ __launch_bounds__(256) void gather_out_kernel(
        const unsigned* __restrict__ crecs, const int* __restrict__ bstartC,
        const int* __restrict__ totalsC, const float* __restrict__ dinv,
        const ushort* __restrict__ xh, const float* __restrict__ x,
        const float* __restrict__ W0, const float* __restrict__ W1,
        const float* __restrict__ bias, float* __restrict__ out) {
    __shared__ __align__(16) char smemA[32 * AST * 4];  // srt (8192B) | xs
    __shared__ __align__(16) char smemB[32 * AST * 4];  // ts
    __shared__ int cnt32[32];
    __shared__ int start32[32];
    __shared__ int cur32[32];
    int2*  srt = (int2*)smemA;
    float* xs  = (float*)smemA;
    float* ts  = (float*)smemB;

    int tid = threadIdx.x;
    int b   = blockIdx.x;
    int n0  = b * 32;
    int g   = tid >> 3;      // node within bucket
    int j   = tid & 7;       // lane owns features 8j..8j+7

    int base = bstartC[b];
    int cnt  = totalsC[b];

    float4 acc0 = make_float4(0.f, 0.f, 0.f, 0.f);
    float4 acc1 = make_float4(0.f, 0.f, 0.f, 0.f);
    const ushort* xhj = xh + (j << 3);

    for (int cb = 0; cb < cnt; cb += CAP) {
        int m = min(CAP, cnt - cb);
        if (tid < 32) cnt32[tid] = 0;
        __syncthreads();
        // pass 1: count by coloff (sequential 4B reads; L2-hot for pass 2)
        for (int i = tid; i < m; i += 256)
            atomicAdd(&cnt32[(crecs[base + cb + i] >> 10) & 31u], 1);
        __syncthreads();
        if (tid < 32) {               // exclusive scan via shfl (wave 0)
            int v = cnt32[tid];
            int inc = v;
            #pragma unroll
            for (int d = 1; d < 32; d <<= 1) {
                int u = __shfl_up(inc, d, 32);
                if (tid >= d) inc += u;
            }
            start32[tid] = inc - v;
            cur32[tid]   = inc - v;
        }
        __syncthreads();
        // pass 2: decode + place (dinv[r] and dequant folded into weight)
        for (int i = tid; i < m; i += 256) {
            unsigned u = crecs[base + cb + i];
            int r = u >> 15;
            float cf = (float)(u & 1023u) * (1.f / 1024.f) * dinv[r];
            int p = atomicAdd(&cur32[(u >> 10) & 31u], 1);
            srt[p] = make_int2(r, __float_as_int(cf));
        }
        __syncthreads();
        // per-node accumulation from bf16 rows (1 uint4 = 8 features / edge)
        int ks = start32[g];
        int ke = cur32[g];
        int k = ks;
        for (; k + 3 < ke; k += 4) {
            int2 e0 = srt[k + 0];
            int2 e1 = srt[k + 1];
            int2 e2 = srt[k + 2];
            int2 e3 = srt[k + 3];
            uint4 u0 = *(const uint4*)(xhj + ((size_t)e0.x << 6));
            uint4 u1 = *(const uint4*)(xhj + ((size_t)e1.x << 6));
            uint4 u2 = *(const uint4*)(xhj + ((size_t)e2.x << 6));
            uint4 u3 = *(const uint4*)(xhj + ((size_t)e3.x << 6));
            FMA_BF16(e0, u0);
            FMA_BF16(e1, u1);
            FMA_BF16(e2, u2);
            FMA_BF16(e3, u3);
        }
        for (; k < ke; ++k) {
            int2 e0 = srt[k];
            uint4 u0 = *(const uint4*)(xhj + ((size_t)e0.x << 6));
            FMA_BF16(e0, u0);
        }
        __syncthreads();   // srt reads done before next chunk / xs overwrite
    }

    // Phase C: ts = -dinv[n]*acc, stage xs (fp32), matmul epilogue.
    float dn = -dinv[n0 + g];
    float* tp = ts + g * AST + (j << 3);
    *(float4*)tp       = make_float4(dn * acc0.x, dn * acc0.y, dn * acc0.z, dn * acc0.w);
    *(float4*)(tp + 4) = make_float4(dn * acc1.x, dn * acc1.y, dn * acc1.z, dn * acc1.w);
    for (int i = tid; i < 512; i += 256) {          // 512 float4 = 32x64 floats
        int nn = i >> 4;
        int kk = (i & 15) << 2;
        *(float4*)&xs[nn * AST + kk] = *(const float4*)(x + (size_t)n0 * D + i * 4);
    }
    __syncthreads();

    int jl = j << 3;
    float4 o0 = *(const float4*)(bias + jl);
    float4 o1 = *(const float4*)(bias + jl + 4);
    for (int k = 0; k < D; k += 4) {
        float4 av = *(const float4*)&xs[g * AST + k];
        float4 tv = *(const float4*)&ts[g * AST + k];
        #pragma unroll
        for (int u = 0; u < 4; ++u) {
            float a = (u == 0) ? av.x : (u == 1) ? av.y : (u == 2) ? av.z : av.w;
            float t = (u == 0) ? tv.x : (u == 1) ? tv.y : (u == 2) ? tv.z : tv.w;
            const float4 w00 = *(const float4*)(W0 + (size_t)(k + u) * D + jl);
            const float4 w01 = *(const float4*)(W0 + (size_t)(k + u) * D + jl + 4);
            const float4 w10 = *(const float4*)(W1 + (size_t)(k + u) * D + jl);
            const float4 w11 = *(const float4*)(W1 + (size_t)(k + u) * D + jl + 4);
            o0.x += a * w00.x + t * w10.x;
            o0.y += a * w00.y + t * w10.y;
            o0.z += a * w00.z + t * w10.z;
            o0.w += a * w00.w + t * w10.w;
            o1.x += a * w01.x + t * w11.x;
            o1.y += a * w01.y + t * w11.y;
            o1.z += a * w01.z + t * w11.z;
            o1.w += a * w01.w + t * w11.w;
        }
    }
    float* op = out + (size_t)(n0 + g) * D + jl;
    *(float4*)op       = o0;
    *(float4*)(op + 4) = o1;
}

extern "C" void kernel_launch(void* const* d_in, const int* in_sizes, int n_in,
                              void* d_out, int out_size, void* d_ws, size_t ws_size,
                              hipStream_t stream) {
    const float* x    = (const float*)d_in[0];
    const int*   eidx = (const int*)d_in[1];   // [2, E]: row then col
    const float* ew   = (const float*)d_in[2];
    const float* W0   = (const float*)d_in[3];
    const float* W1   = (const float*)d_in[4];
    const float* b    = (const float*)d_in[5];
    float* out = (float*)d_out;

    const int* row = eidx;
    const int* col = eidx + N_EDGES;

    // Workspace layout (4B words), fully overwritten each call, no memset.
    // crecs 6.4MB + rrecs 6.4MB + mats 3.2MB + small + dinv 0.4MB + xh 12.8MB
    // ~= 29.3 MB total.
    unsigned* crecs   = (unsigned*)d_ws;                               // E
    unsigned* rrecs   = crecs + N_EDGES;                               // E
    int*      matC    = (int*)(rrecs + N_EDGES);                       // NB*NBUCK_PAD
    int*      matR    = matC + (size_t)NB * NBUCK_PAD;                 // NB*NBUCK_PAD
    int*      totalsC = matR + (size_t)NB * NBUCK_PAD;                 // NBUCK_PAD
    int*      bstartC = totalsC + NBUCK_PAD;                           // NBUCK_PAD
    int*      totalsR = bstartC + NBUCK_PAD;                           // NBUCK_PAD
    int*      bstartR = totalsR + NBUCK_PAD;                           // NBUCK_PAD
    float*    dinv    = (float*)(bstartR + NBUCK_PAD);                 // N
    ushort*   xh      = (ushort*)(dinv + N_NODES);                     // N*D ushort

    tobf16_kernel    <<<N_NODES * D / (256 * 8), 256, 0, stream>>>(x, xh);
    count_kernel     <<<NB, 512, 0, stream>>>(row, col, matC, matR);
    blockscan_kernel <<<2 * NGRP, 256, 0, stream>>>(matC, matR, totalsC, totalsR);
    totscan_kernel   <<<2, 256, 0, stream>>>(totalsC, bstartC, totalsR, bstartR);
    scatter_kernel   <<<NB, 512, 0, stream>>>(row, col, ew, matC, matR,
                                              bstartC, bstartR, crecs, rrecs);
    deg_kernel       <<<NBUCK, 256, 0, stream>>>(rrecs, bstartR, totalsR, dinv);
    gather_out_kernel<<<NBUCK, 256, 0, stream>>>(crecs, bstartC, totalsC, dinv,
                                                 xh, x, W0, W1, b, out);
}